// Round 5
// baseline (269.433 us; speedup 1.0000x reference)
//
#include <hip/hip_runtime.h>

// 5-layer MLP [B,64]->32->12->8->6->2, fp32. Wave-autonomous LDS pipeline:
// each wave owns 64 rows/tile in a 2x16KB LDS double buffer, staged with
// global_load_lds (width 16, coalesced 1KB/instr), prefetch overlapped with
// compute via counted s_waitcnt vmcnt(16). No __syncthreads (LDS is
// wave-private). LDS reads XOR-swizzled (chunk c of row r at slot c^(r&7),
// applied on the pre-swizzled GLOBAL source per T21) -> conflict-free
// ds_read_b128. One thread per row; weights on the scalar pipe.

#define BLOCK 128          // 2 waves per block
#define NT 16              // tiles per wave
#define TILE_ROWS 64       // rows per wave-tile (= lanes)
#define ROW_BYTES 256      // 64 fp32
#define TILE_BYTES 16384   // 64 rows * 256 B

typedef __attribute__((address_space(3))) void* as3p;
typedef const __attribute__((address_space(1))) void* as1p;

template <int IN, int OUT, bool RELU>
__device__ __forceinline__ void layer(const float* __restrict__ W,
                                      const float* __restrict__ b,
                                      const float* h_in, float* h_out) {
#pragma unroll
    for (int o = 0; o < OUT; ++o) h_out[o] = b[o];
#pragma unroll
    for (int i = 0; i < IN; ++i) {
        const float v = h_in[i];
#pragma unroll
        for (int o = 0; o < OUT; ++o)
            h_out[o] = fmaf(v, W[i * OUT + o], h_out[o]);
    }
    if (RELU) {
#pragma unroll
        for (int o = 0; o < OUT; ++o) h_out[o] = fmaxf(h_out[o], 0.0f);
    }
}

// Stage one 64-row tile: 16 calls, each wave-uniform LDS dest + lane*16B,
// per-lane global source pre-swizzled so that LDS slot s of row r holds
// global chunk s ^ (r&7).
__device__ __forceinline__ void stage_tile(const char* __restrict__ xtile,
                                           char* buf, int lane) {
#pragma unroll
    for (int k = 0; k < 16; ++k) {
        const int r = 4 * k + (lane >> 4);       // local row this lane feeds
        const int c = (lane & 15) ^ (r & 7);     // global chunk for its slot
        __builtin_amdgcn_global_load_lds(
            (as1p)(xtile + r * ROW_BYTES + c * 16),
            (as3p)(buf + k * 1024), 16, 0, 0);
    }
}

__global__ __launch_bounds__(BLOCK) void mlp_kernel(
        const float* __restrict__ x,
        const float* __restrict__ W0, const float* __restrict__ b0,
        const float* __restrict__ W1, const float* __restrict__ b1,
        const float* __restrict__ W2, const float* __restrict__ b2,
        const float* __restrict__ W3, const float* __restrict__ b3,
        const float* __restrict__ W4, const float* __restrict__ b4,
        float* __restrict__ out, int nrows) {
    extern __shared__ char lds[];
    const int wv = threadIdx.x >> 6;
    const int lane = threadIdx.x & 63;
    char* buf0 = lds + wv * (2 * TILE_BYTES);
    char* buf1 = buf0 + TILE_BYTES;

    const long long gw = (long long)blockIdx.x * 2 + wv;   // global wave id
    const long long row0 = gw * (long long)(NT * TILE_ROWS);
    const char* xbase = (const char*)(x + row0 * 64);

    stage_tile(xbase, buf0, lane);                          // prologue

#pragma unroll 1
    for (int it = 0; it < NT; ++it) {
        char* cur = (it & 1) ? buf1 : buf0;
        char* nxt = (it & 1) ? buf0 : buf1;
        if (it + 1 < NT) {
            stage_tile(xbase + (long long)(it + 1) * TILE_BYTES, nxt, lane);
            // 16 new loads outstanding; wait for the 16 of the CURRENT tile
            // (vmcnt retires in order, so the interleaved store also drains).
            asm volatile("s_waitcnt vmcnt(16)" ::: "memory");
        } else {
            asm volatile("s_waitcnt vmcnt(0)" ::: "memory");
        }

        // Swizzled conflict-free row read: 16x ds_read_b128.
        const char* rowp = cur + lane * ROW_BYTES;
        float xr[64];
#pragma unroll
        for (int c = 0; c < 16; ++c) {
            const float4 v = *reinterpret_cast<const float4*>(
                rowp + (((c ^ (lane & 7)) << 4)));
            xr[4 * c + 0] = v.x; xr[4 * c + 1] = v.y;
            xr[4 * c + 2] = v.z; xr[4 * c + 3] = v.w;
        }

        float h0[32];
        layer<64, 32, true>(W0, b0, xr, h0);
        float h1[12];
        layer<32, 12, true>(W1, b1, h0, h1);
        float h2[8];
        layer<12, 8, true>(W2, b2, h1, h2);
        float h3[6];
        layer<8, 6, true>(W3, b3, h2, h3);
        float h4[2];
        layer<6, 2, false>(W4, b4, h3, h4);

        const long long row = row0 + (long long)it * TILE_ROWS + lane;
        reinterpret_cast<float2*>(out)[row] = make_float2(h4[0], h4[1]);
    }
}

extern "C" void kernel_launch(void* const* d_in, const int* in_sizes, int n_in,
                              void* d_out, int out_size, void* d_ws, size_t ws_size,
                              hipStream_t stream) {
    const float* x  = (const float*)d_in[0];
    const float* W0 = (const float*)d_in[1];
    const float* b0 = (const float*)d_in[2];
    const float* W1 = (const float*)d_in[3];
    const float* b1 = (const float*)d_in[4];
    const float* W2 = (const float*)d_in[5];
    const float* b2 = (const float*)d_in[6];
    const float* W3 = (const float*)d_in[7];
    const float* b3 = (const float*)d_in[8];
    const float* W4 = (const float*)d_in[9];
    const float* b4 = (const float*)d_in[10];
    float* out = (float*)d_out;

    const int nrows = in_sizes[0] / 64;                    // 1,048,576
    const int rows_per_block = 2 * NT * TILE_ROWS;         // 2048
    const int grid = nrows / rows_per_block;               // 512 (exact)
    const size_t shmem = 2 * 2 * TILE_BYTES;               // 64 KiB

    mlp_kernel<<<grid, BLOCK, shmem, stream>>>(x, W0, b0, W1, b1, W2, b2,
                                               W3, b3, W4, b4, out, nrows);
}

// Round 6
// 124.790 us; speedup vs baseline: 2.1591x; 2.1591x over previous
//
#include <hip/hip_runtime.h>

// 5-layer MLP [B,64]->32->12->8->6->2, fp32. Wave-autonomous pipeline:
// each wave owns 64 rows, staged in FOUR 4KB column-chunks (64 rows x 64B),
// double-buffered (8KB/wave) via global_load_lds + counted s_waitcnt vmcnt(4).
// No __syncthreads (LDS regions are wave-private). Layer 0 accumulates over
// column chunks; tail layers run fully per-lane. LDS layout pairs rows into
// 128B super-rows with XOR slot swizzle S=(j+4p)^(R&7): reads are 8 lanes per
// bank-quad (conflict-free optimal for ds_read_b128), and the matching
// inverse permutation on the per-lane GLOBAL source is a per-lane constant
// with each lane's 16B inside one 64B line (fully coalesced).

typedef float v2f __attribute__((ext_vector_type(2)));
typedef __attribute__((address_space(3))) void* as3p;
typedef const __attribute__((address_space(1))) void* as1p;

#define BLOCK 256   // 4 waves/block
#define CHUNK_BYTES 4096
#define WAVE_LDS    8192   // 2 x 4KB

template <int IN, int OUT, bool RELU>
__device__ __forceinline__ void vlayer(const float* __restrict__ W,
                                       const float* __restrict__ b,
                                       const v2f* hin, v2f* hout) {
#pragma unroll
    for (int o = 0; o < OUT / 2; ++o)
        hout[o] = *reinterpret_cast<const v2f*>(&b[2 * o]);
#pragma unroll
    for (int i = 0; i < IN; ++i) {
        const float v = hin[i >> 1][i & 1];
        const v2f xv = {v, v};
#pragma unroll
        for (int o = 0; o < OUT / 2; ++o) {
            const v2f w = *reinterpret_cast<const v2f*>(&W[i * OUT + 2 * o]);
            hout[o] = __builtin_elementwise_fma(w, xv, hout[o]);
        }
    }
    if (RELU) {
#pragma unroll
        for (int o = 0; o < OUT / 2; ++o) {
            hout[o][0] = fmaxf(hout[o][0], 0.0f);
            hout[o][1] = fmaxf(hout[o][1], 0.0f);
        }
    }
}

__global__ __launch_bounds__(BLOCK) void mlp_kernel(
        const float* __restrict__ x,
        const float* __restrict__ W0, const float* __restrict__ b0,
        const float* __restrict__ W1, const float* __restrict__ b1,
        const float* __restrict__ W2, const float* __restrict__ b2,
        const float* __restrict__ W3, const float* __restrict__ b3,
        const float* __restrict__ W4, const float* __restrict__ b4,
        float* __restrict__ out, int nrows) {
    extern __shared__ char lds[];
    const int t = threadIdx.x;
    const int wv = t >> 6;
    const int lane = t & 63;
    char* buf0 = lds + wv * WAVE_LDS;
    char* buf1 = buf0 + CHUNK_BYTES;

    const long long row0 = ((long long)blockIdx.x * 4 + wv) * 64;
    const char* xt = reinterpret_cast<const char*>(x + row0 * 64);  // 64 rows x 256B

    // ---- per-lane constant source offset for staging (inverse swizzle) ----
    // LDS slot (k,lane) = super-row R=k*8+(lane>>3), slot S=lane&7 holds
    // global (row r, 16B-subcol j): q=(lane&7)^(lane>>3), p=q>>2, j=q&3,
    // r = 16k + 2*(lane>>3) + p.
    const int h = lane >> 3;
    const int q = (lane & 7) ^ h;
    const int stage_off = (2 * h + (q >> 2)) * 256 + (q & 3) * 16;

    // ---- per-lane constant LDS read offsets (row r = lane) ----
    const int R = lane >> 1;
    const int p2 = lane & 1;
    const int r7 = R & 7;
    int roff[4];
#pragma unroll
    for (int j = 0; j < 4; ++j)
        roff[j] = R * 128 + (((j + 4 * p2) ^ r7) << 4);

    // ---- prologue: stage chunk 0 ----
#pragma unroll
    for (int k = 0; k < 4; ++k)
        __builtin_amdgcn_global_load_lds((as1p)(xt + k * 4096 + stage_off),
                                         (as3p)(buf0 + k * 1024), 16, 0, 0);

    v2f acc[16];
#pragma unroll
    for (int o = 0; o < 16; ++o)
        acc[o] = *reinterpret_cast<const v2f*>(&b0[2 * o]);

#pragma unroll
    for (int c = 0; c < 4; ++c) {
        char* cur = (c & 1) ? buf1 : buf0;
        char* nxt = (c & 1) ? buf0 : buf1;
        if (c < 3) {
#pragma unroll
            for (int k = 0; k < 4; ++k)
                __builtin_amdgcn_global_load_lds(
                    (as1p)(xt + (c + 1) * 64 + k * 4096 + stage_off),
                    (as3p)(nxt + k * 1024), 16, 0, 0);
            // keep next chunk's 4 loads in flight; wait only for current's
            asm volatile("s_waitcnt vmcnt(4)" ::: "memory");
        } else {
            asm volatile("s_waitcnt vmcnt(0)" ::: "memory");
        }
        __builtin_amdgcn_sched_barrier(0);

        // conflict-free swizzled reads: 4x ds_read_b128
        float xr[16];
#pragma unroll
        for (int j = 0; j < 4; ++j) {
            const float4 v = *reinterpret_cast<const float4*>(cur + roff[j]);
            xr[4 * j + 0] = v.x; xr[4 * j + 1] = v.y;
            xr[4 * j + 2] = v.z; xr[4 * j + 3] = v.w;
        }

        // layer-0 partial: 16 i-values x 32 outputs (pk-fma)
#pragma unroll
        for (int idx = 0; idx < 16; ++idx) {
            const int i = c * 16 + idx;
            const v2f xv = {xr[idx], xr[idx]};
#pragma unroll
            for (int o = 0; o < 16; ++o) {
                const v2f w = *reinterpret_cast<const v2f*>(&W0[i * 32 + 2 * o]);
                acc[o] = __builtin_elementwise_fma(w, xv, acc[o]);
            }
        }
    }

    // ReLU on h0
#pragma unroll
    for (int o = 0; o < 16; ++o) {
        acc[o][0] = fmaxf(acc[o][0], 0.0f);
        acc[o][1] = fmaxf(acc[o][1], 0.0f);
    }

    v2f h1[6], h2[4], h3[3], h4[1];
    vlayer<32, 12, true>(W1, b1, acc, h1);
    vlayer<12, 8, true>(W2, b2, h1, h2);
    vlayer<8, 6, true>(W3, b3, h2, h3);
    vlayer<6, 2, false>(W4, b4, h3, h4);

    reinterpret_cast<float2*>(out)[row0 + lane] = make_float2(h4[0][0], h4[0][1]);
}

extern "C" void kernel_launch(void* const* d_in, const int* in_sizes, int n_in,
                              void* d_out, int out_size, void* d_ws, size_t ws_size,
                              hipStream_t stream) {
    const float* x  = (const float*)d_in[0];
    const float* W0 = (const float*)d_in[1];
    const float* b0 = (const float*)d_in[2];
    const float* W1 = (const float*)d_in[3];
    const float* b1 = (const float*)d_in[4];
    const float* W2 = (const float*)d_in[5];
    const float* b2 = (const float*)d_in[6];
    const float* W3 = (const float*)d_in[7];
    const float* b3 = (const float*)d_in[8];
    const float* W4 = (const float*)d_in[9];
    const float* b4 = (const float*)d_in[10];
    float* out = (float*)d_out;

    const int nrows = in_sizes[0] / 64;          // 1,048,576
    const int grid = nrows / BLOCK;              // 4096 (exact)
    const size_t shmem = 4 * WAVE_LDS;           // 32 KiB/block

    mlp_kernel<<<grid, BLOCK, shmem, stream>>>(x, W0, b0, W1, b1, W2, b2,
                                               W3, b3, W4, b4, out, nrows);
}